// Round 1
// baseline (93.973 us; speedup 1.0000x reference)
//
#include <hip/hip_runtime.h>
#include <math.h>

#define NB 4
#define NQ 256
#define NK 1024
#define ND 512
#define NA 128

// ws layout in floats
#define OFF_H1 0u                 // NB*NQ*NA   = 131072
#define OFF_H2 131072u            // NB*NK*NA   = 524288
#define OFF_SC 655360u            // NB*NQ*NK   = 1048576
#define OFF_PT 1703936u           // 8*NB*NQ*ND = 4194304  (total 23.6 MB)

// ---------------- Kernel 1: projections h1 = query@Wq^T+bq, h2 = key@Wk^T+bk
// rows 0..1023 -> h1 (query), rows 1024..5119 -> h2 (key). 32 rows/block.
__global__ __launch_bounds__(256) void k_proj(
    const float* __restrict__ query, const float* __restrict__ key,
    const float* __restrict__ Wq, const float* __restrict__ bq,
    const float* __restrict__ Wk, const float* __restrict__ bk,
    float* __restrict__ h1, float* __restrict__ h2)
{
    __shared__ float Xt[32 * 36];    // [k][m], stride 36 (16B-aligned rows)
    __shared__ float Wt[32 * 132];   // [k][n], stride 132
    const int tid = threadIdx.x;
    const int r0 = blockIdx.x * 32;

    const float* Xb; const float* W; const float* bias; float* hb;
    if (r0 < NB * NQ) {
        Xb = query + (size_t)r0 * ND; W = Wq; bias = bq; hb = h1 + (size_t)r0 * NA;
    } else {
        const int rk = r0 - NB * NQ;
        Xb = key + (size_t)rk * ND; W = Wk; bias = bk; hb = h2 + (size_t)rk * NA;
    }

    float acc[4][4] = {};
    const int tm = tid >> 5;   // 0..7  -> rows tm*4..+3
    const int tn = tid & 31;   // 0..31 -> cols tn*4..+3

    for (int kc = 0; kc < ND; kc += 32) {
        __syncthreads();
        {   // stage X chunk: 32 rows x 32 k (1 float4/thread), transposed
            const int m = tid >> 3, k4 = tid & 7;
            const float4 v = *(const float4*)(Xb + (size_t)m * ND + kc + k4 * 4);
            Xt[(k4 * 4 + 0) * 36 + m] = v.x; Xt[(k4 * 4 + 1) * 36 + m] = v.y;
            Xt[(k4 * 4 + 2) * 36 + m] = v.z; Xt[(k4 * 4 + 3) * 36 + m] = v.w;
        }
        #pragma unroll
        for (int j = 0; j < 4; ++j) {  // stage W chunk: 128 n x 32 k, transposed
            const int i4 = tid + j * 256;
            const int n = i4 >> 3, k4 = i4 & 7;
            const float4 v = *(const float4*)(W + (size_t)n * ND + kc + k4 * 4);
            Wt[(k4 * 4 + 0) * 132 + n] = v.x; Wt[(k4 * 4 + 1) * 132 + n] = v.y;
            Wt[(k4 * 4 + 2) * 132 + n] = v.z; Wt[(k4 * 4 + 3) * 132 + n] = v.w;
        }
        __syncthreads();
        #pragma unroll 8
        for (int k = 0; k < 32; ++k) {
            const float4 xa = *(const float4*)(Xt + k * 36 + tm * 4);
            const float4 wb = *(const float4*)(Wt + k * 132 + tn * 4);
            const float xv[4] = {xa.x, xa.y, xa.z, xa.w};
            const float wv[4] = {wb.x, wb.y, wb.z, wb.w};
            #pragma unroll
            for (int i = 0; i < 4; ++i)
                #pragma unroll
                for (int j = 0; j < 4; ++j)
                    acc[i][j] = fmaf(xv[i], wv[j], acc[i][j]);
        }
    }

    const float4 bv = *(const float4*)(bias + tn * 4);
    const float bb[4] = {bv.x, bv.y, bv.z, bv.w};
    #pragma unroll
    for (int i = 0; i < 4; ++i) {
        float4 o;
        o.x = acc[i][0] + bb[0]; o.y = acc[i][1] + bb[1];
        o.z = acc[i][2] + bb[2]; o.w = acc[i][3] + bb[3];
        *(float4*)(hb + (size_t)(tm * 4 + i) * NA + tn * 4) = o;
    }
}

// ---------------- Kernel 2: logits + softmax -> score
// block = (b, 4 q-rows). thread handles k = tid + 256c (c=0..3) for all 4 q.
// h2 rows are thread-private -> read straight from global (L2), no LDS staging.
__global__ __launch_bounds__(256) void k_logits_softmax(
    const float* __restrict__ h1, const float* __restrict__ h2,
    const float* __restrict__ Wa, float* __restrict__ score)
{
    __shared__ float h1s[4 * 128];
    __shared__ float was[128];
    __shared__ float redm[4][4];
    __shared__ float reds[4][4];
    const int tid = threadIdx.x;
    const int b = blockIdx.x >> 6;
    const int q0 = (blockIdx.x & 63) << 2;

    #pragma unroll
    for (int j = 0; j < 2; ++j) {
        const int i = tid + j * 256;           // 0..511
        const int q = i >> 7, a = i & 127;
        h1s[q * 128 + a] = h1[(size_t)(b * NQ + q0 + q) * NA + a];
    }
    if (tid < 128) was[tid] = Wa[tid];
    __syncthreads();

    const float4* __restrict__ h2b  = (const float4*)(h2 + (size_t)b * NK * NA);
    const float4* __restrict__ h1s4 = (const float4*)h1s;
    const float4* __restrict__ was4 = (const float4*)was;

    float lg[4][4];
    #pragma unroll
    for (int c = 0; c < 4; ++c) {
        const int k = tid + c * 256;
        const float4* row = h2b + (size_t)k * 32;
        float s0 = 0.f, s1 = 0.f, s2 = 0.f, s3 = 0.f;
        #pragma unroll 8
        for (int a4 = 0; a4 < 32; ++a4) {
            const float4 hv = row[a4];
            const float4 wv = was4[a4];
            const float4 p0 = h1s4[0 * 32 + a4];
            const float4 p1 = h1s4[1 * 32 + a4];
            const float4 p2 = h1s4[2 * 32 + a4];
            const float4 p3 = h1s4[3 * 32 + a4];
            s0 = fmaf(wv.x, fmaxf(p0.x + hv.x, 0.f), s0);
            s0 = fmaf(wv.y, fmaxf(p0.y + hv.y, 0.f), s0);
            s0 = fmaf(wv.z, fmaxf(p0.z + hv.z, 0.f), s0);
            s0 = fmaf(wv.w, fmaxf(p0.w + hv.w, 0.f), s0);
            s1 = fmaf(wv.x, fmaxf(p1.x + hv.x, 0.f), s1);
            s1 = fmaf(wv.y, fmaxf(p1.y + hv.y, 0.f), s1);
            s1 = fmaf(wv.z, fmaxf(p1.z + hv.z, 0.f), s1);
            s1 = fmaf(wv.w, fmaxf(p1.w + hv.w, 0.f), s1);
            s2 = fmaf(wv.x, fmaxf(p2.x + hv.x, 0.f), s2);
            s2 = fmaf(wv.y, fmaxf(p2.y + hv.y, 0.f), s2);
            s2 = fmaf(wv.z, fmaxf(p2.z + hv.z, 0.f), s2);
            s2 = fmaf(wv.w, fmaxf(p2.w + hv.w, 0.f), s2);
            s3 = fmaf(wv.x, fmaxf(p3.x + hv.x, 0.f), s3);
            s3 = fmaf(wv.y, fmaxf(p3.y + hv.y, 0.f), s3);
            s3 = fmaf(wv.z, fmaxf(p3.z + hv.z, 0.f), s3);
            s3 = fmaf(wv.w, fmaxf(p3.w + hv.w, 0.f), s3);
        }
        lg[0][c] = s0; lg[1][c] = s1; lg[2][c] = s2; lg[3][c] = s3;
    }
    // NOTE: +ba omitted — constant over k, cancels in softmax.

    const int wv_ = tid >> 6, ln = tid & 63;
    float mq[4];
    #pragma unroll
    for (int q = 0; q < 4; ++q) {
        float m = fmaxf(fmaxf(lg[q][0], lg[q][1]), fmaxf(lg[q][2], lg[q][3]));
        for (int off = 32; off > 0; off >>= 1) m = fmaxf(m, __shfl_xor(m, off));
        if (ln == 0) redm[q][wv_] = m;
    }
    __syncthreads();
    #pragma unroll
    for (int q = 0; q < 4; ++q)
        mq[q] = fmaxf(fmaxf(redm[q][0], redm[q][1]), fmaxf(redm[q][2], redm[q][3]));
    #pragma unroll
    for (int q = 0; q < 4; ++q) {
        float s = 0.f;
        #pragma unroll
        for (int c = 0; c < 4; ++c) { lg[q][c] = __expf(lg[q][c] - mq[q]); s += lg[q][c]; }
        for (int off = 32; off > 0; off >>= 1) s += __shfl_xor(s, off);
        if (ln == 0) reds[q][wv_] = s;
    }
    __syncthreads();
    #pragma unroll
    for (int q = 0; q < 4; ++q) {
        const float inv = 1.f / (reds[q][0] + reds[q][1] + reds[q][2] + reds[q][3]);
        float* so = score + (size_t)(b * NQ + q0 + q) * NK + tid;
        #pragma unroll
        for (int c = 0; c < 4; ++c) so[c * 256] = lg[q][c] * inv;
    }
}

// ---------------- Kernel 3: PV partial GEMM. 128x128 tile, 8x8 micro, K-split 8.
__global__ __launch_bounds__(256) void k_pv(
    const float* __restrict__ score, const float* __restrict__ value,
    float* __restrict__ partial)
{
    __shared__ float St[32 * 132];   // [k][m]
    __shared__ float Vt[32 * 132];   // [k][n]
    const int tid = threadIdx.x;
    const int m0 = blockIdx.x * 128;          // 0..1
    const int n0 = blockIdx.y * 128;          // 0..3
    const int b  = blockIdx.z >> 3;           // 0..3
    const int ks = blockIdx.z & 7;            // 0..7
    const int k0 = ks * 128;

    float acc[8][8] = {};
    const int tm = tid >> 4, tn = tid & 15;

    for (int kc = 0; kc < 128; kc += 32) {
        __syncthreads();
        #pragma unroll
        for (int j = 0; j < 4; ++j) {   // stage score 128m x 32k, transposed
            const int i4 = tid + j * 256;
            const int m = i4 >> 3, k4 = i4 & 7;
            const float4 v = *(const float4*)(score +
                (size_t)(b * NQ + m0 + m) * NK + k0 + kc + k4 * 4);
            St[(k4 * 4 + 0) * 132 + m] = v.x; St[(k4 * 4 + 1) * 132 + m] = v.y;
            St[(k4 * 4 + 2) * 132 + m] = v.z; St[(k4 * 4 + 3) * 132 + m] = v.w;
        }
        #pragma unroll
        for (int j = 0; j < 4; ++j) {   // stage value 32k x 128n (row-major)
            const int i4 = tid + j * 256;
            const int r = i4 >> 5, n4 = i4 & 31;
            const float4 v = *(const float4*)(value +
                (size_t)(b * NK + k0 + kc + r) * ND + n0 + n4 * 4);
            *(float4*)(Vt + r * 132 + n4 * 4) = v;
        }
        __syncthreads();
        #pragma unroll 4
        for (int k = 0; k < 32; ++k) {
            const float4 a0 = *(const float4*)(St + k * 132 + tm * 8);
            const float4 a1 = *(const float4*)(St + k * 132 + tm * 8 + 4);
            const float4 b0 = *(const float4*)(Vt + k * 132 + tn * 8);
            const float4 b1 = *(const float4*)(Vt + k * 132 + tn * 8 + 4);
            const float av[8] = {a0.x, a0.y, a0.z, a0.w, a1.x, a1.y, a1.z, a1.w};
            const float bvv[8] = {b0.x, b0.y, b0.z, b0.w, b1.x, b1.y, b1.z, b1.w};
            #pragma unroll
            for (int i = 0; i < 8; ++i)
                #pragma unroll
                for (int j = 0; j < 8; ++j)
                    acc[i][j] = fmaf(av[i], bvv[j], acc[i][j]);
        }
    }

    float* pb = partial + (size_t)ks * (NB * NQ * ND);
    #pragma unroll
    for (int i = 0; i < 8; ++i) {
        float* po = pb + (size_t)(b * NQ + m0 + tm * 8 + i) * ND + n0 + tn * 8;
        float4 o0, o1;
        o0.x = acc[i][0]; o0.y = acc[i][1]; o0.z = acc[i][2]; o0.w = acc[i][3];
        o1.x = acc[i][4]; o1.y = acc[i][5]; o1.z = acc[i][6]; o1.w = acc[i][7];
        *(float4*)(po) = o0;
        *(float4*)(po + 4) = o1;
    }
}

// ---------------- Kernel 4: reduce 8 partials -> d_out
__global__ __launch_bounds__(256) void k_reduce(
    const float* __restrict__ partial, float* __restrict__ out)
{
    const int t = blockIdx.x * 256 + threadIdx.x;    // 0..131071 float4s
    const float4* p = (const float4*)partial;
    float4 s = p[t];
    #pragma unroll
    for (int ks = 1; ks < 8; ++ks) {
        const float4 v = p[(size_t)ks * 131072 + t];
        s.x += v.x; s.y += v.y; s.z += v.z; s.w += v.w;
    }
    ((float4*)out)[t] = s;
}

extern "C" void kernel_launch(void* const* d_in, const int* in_sizes, int n_in,
                              void* d_out, int out_size, void* d_ws, size_t ws_size,
                              hipStream_t stream) {
    const float* key   = (const float*)d_in[0];
    const float* query = (const float*)d_in[1];
    const float* value = (const float*)d_in[2];
    const float* Wk    = (const float*)d_in[3];
    const float* bk    = (const float*)d_in[4];
    const float* Wq    = (const float*)d_in[5];
    const float* bq    = (const float*)d_in[6];
    const float* Wa    = (const float*)d_in[7];
    // d_in[8] = ba: constant over k, cancels in softmax — unused.

    float* ws = (float*)d_ws;
    float* h1 = ws + OFF_H1;
    float* h2 = ws + OFF_H2;
    float* sc = ws + OFF_SC;
    float* pt = ws + OFF_PT;

    k_proj<<<160, 256, 0, stream>>>(query, key, Wq, bq, Wk, bk, h1, h2);
    k_logits_softmax<<<256, 256, 0, stream>>>(h1, h2, Wa, sc);
    k_pv<<<dim3(2, 4, 32), 256, 0, stream>>>(sc, value, pt);
    k_reduce<<<512, 256, 0, stream>>>(pt, (float*)d_out);
}

// Round 3
// 76.003 us; speedup vs baseline: 1.2364x; 1.2364x over previous
//
#include <hip/hip_runtime.h>
#include <hip/hip_bf16.h>
#include <math.h>

#define NB 4
#define NQ 256
#define NK 1024
#define ND 512
#define NA 128

// ws layout (bytes)
#define OFFB_H1 0u          // NB*NQ*NA f32 = 512 KB
#define OFFB_H2 524288u     // NB*NK*NA f32 = 2 MB
#define OFFB_SC 2621440u    // NB*NQ*NK bf16 = 2 MB
#define OFFB_VT 4718592u    // NB*ND*NK bf16 = 4 MB   (total 8.5 MB)

typedef __attribute__((ext_vector_type(8))) short short8;
typedef __attribute__((ext_vector_type(4))) float f32x4;

static __device__ __forceinline__ ushort f2bf(float x) {
    __hip_bfloat16 h = __float2bfloat16(x);   // RNE
    return *reinterpret_cast<ushort*>(&h);
}

// ---------------- Kernel 1: fused {projections | value transpose+cvt}
// blocks 0..159: h1 = query@Wq^T+bq (rows 0..1023), h2 = key@Wk^T+bk (rows 1024..5119)
// blocks 160..671: vt[b][d][k] = bf16(value[b][k][d])
__global__ __launch_bounds__(256) void k_proj_vt(
    const float* __restrict__ query, const float* __restrict__ key,
    const float* __restrict__ value,
    const float* __restrict__ Wq, const float* __restrict__ bq,
    const float* __restrict__ Wk, const float* __restrict__ bk,
    float* __restrict__ h1, float* __restrict__ h2,
    __hip_bfloat16* __restrict__ vt)
{
    __shared__ float smem[5376];   // proj: Xt[32*36]+Wt[32*132]; vt: ushort[64][65]
    const int tid = threadIdx.x;
    const int bid = blockIdx.x;

    if (bid < 160) {
        float* Xt = smem;             // [k][m] stride 36
        float* Wt = smem + 32 * 36;   // [k][n] stride 132
        const int r0 = bid * 32;

        const float* Xb; const float* W; const float* bias; float* hb;
        if (r0 < NB * NQ) {
            Xb = query + (size_t)r0 * ND; W = Wq; bias = bq; hb = h1 + (size_t)r0 * NA;
        } else {
            const int rk = r0 - NB * NQ;
            Xb = key + (size_t)rk * ND; W = Wk; bias = bk; hb = h2 + (size_t)rk * NA;
        }

        float acc[4][4] = {};
        const int tm = tid >> 5, tn = tid & 31;

        for (int kc = 0; kc < ND; kc += 32) {
            __syncthreads();
            {   // stage X chunk 32m x 32k transposed
                const int m = tid >> 3, k4 = tid & 7;
                const float4 v = *(const float4*)(Xb + (size_t)m * ND + kc + k4 * 4);
                Xt[(k4 * 4 + 0) * 36 + m] = v.x; Xt[(k4 * 4 + 1) * 36 + m] = v.y;
                Xt[(k4 * 4 + 2) * 36 + m] = v.z; Xt[(k4 * 4 + 3) * 36 + m] = v.w;
            }
            #pragma unroll
            for (int j = 0; j < 4; ++j) {  // stage W chunk 128n x 32k transposed
                const int i4 = tid + j * 256;
                const int n = i4 >> 3, k4 = i4 & 7;
                const float4 v = *(const float4*)(W + (size_t)n * ND + kc + k4 * 4);
                Wt[(k4 * 4 + 0) * 132 + n] = v.x; Wt[(k4 * 4 + 1) * 132 + n] = v.y;
                Wt[(k4 * 4 + 2) * 132 + n] = v.z; Wt[(k4 * 4 + 3) * 132 + n] = v.w;
            }
            __syncthreads();
            #pragma unroll 8
            for (int k = 0; k < 32; ++k) {
                const float4 xa = *(const float4*)(Xt + k * 36 + tm * 4);
                const float4 wb = *(const float4*)(Wt + k * 132 + tn * 4);
                const float xv[4] = {xa.x, xa.y, xa.z, xa.w};
                const float wv[4] = {wb.x, wb.y, wb.z, wb.w};
                #pragma unroll
                for (int i = 0; i < 4; ++i)
                    #pragma unroll
                    for (int j = 0; j < 4; ++j)
                        acc[i][j] = fmaf(xv[i], wv[j], acc[i][j]);
            }
        }

        const float4 bv = *(const float4*)(bias + tn * 4);
        const float bb[4] = {bv.x, bv.y, bv.z, bv.w};
        #pragma unroll
        for (int i = 0; i < 4; ++i) {
            float4 o;
            o.x = acc[i][0] + bb[0]; o.y = acc[i][1] + bb[1];
            o.z = acc[i][2] + bb[2]; o.w = acc[i][3] + bb[3];
            *(float4*)(hb + (size_t)(tm * 4 + i) * NA + tn * 4) = o;
        }
    } else {
        // value transpose + bf16 convert: 64k x 64d tile
        ushort (*tile)[65] = (ushort (*)[65])smem;
        const int id = bid - 160;          // 0..511
        const int kt = id & 15;            // 16 k-tiles
        const int dt = (id >> 4) & 7;      // 8 d-tiles
        const int b  = id >> 7;            // 4 batches
        const int k0 = kt * 64, d0 = dt * 64;
        const int tr = tid >> 4, tc4 = (tid & 15) * 4;

        #pragma unroll
        for (int p = 0; p < 4; ++p) {
            const int r = p * 16 + tr;     // k-row within tile
            const float4 v = *(const float4*)(value + ((size_t)(b * NK + k0 + r)) * ND + d0 + tc4);
            tile[r][tc4 + 0] = f2bf(v.x); tile[r][tc4 + 1] = f2bf(v.y);
            tile[r][tc4 + 2] = f2bf(v.z); tile[r][tc4 + 3] = f2bf(v.w);
        }
        __syncthreads();
        ushort* vo = (ushort*)vt;
        #pragma unroll
        for (int p = 0; p < 4; ++p) {
            const int d = p * 16 + tr;     // d-row within tile
            ushort4 o;
            o.x = tile[tc4 + 0][d]; o.y = tile[tc4 + 1][d];
            o.z = tile[tc4 + 2][d]; o.w = tile[tc4 + 3][d];
            *(ushort4*)(vo + ((size_t)(b * ND + d0 + d)) * NK + k0 + tc4) = o;
        }
    }
}

// ---------------- Kernel 2: logits + softmax -> score (bf16)
// block = (b, 4 q-rows). thread handles k = tid + 256c (c=0..3) for all 4 q.
__global__ __launch_bounds__(256) void k_logits_softmax(
    const float* __restrict__ h1, const float* __restrict__ h2,
    const float* __restrict__ Wa, __hip_bfloat16* __restrict__ score)
{
    __shared__ float h1s[4 * 128];
    __shared__ float was[128];
    __shared__ float redm[4][4];
    __shared__ float reds[4][4];
    const int tid = threadIdx.x;
    const int b = blockIdx.x >> 6;
    const int q0 = (blockIdx.x & 63) << 2;

    #pragma unroll
    for (int j = 0; j < 2; ++j) {
        const int i = tid + j * 256;
        const int q = i >> 7, a = i & 127;
        h1s[q * 128 + a] = h1[(size_t)(b * NQ + q0 + q) * NA + a];
    }
    if (tid < 128) was[tid] = Wa[tid];
    __syncthreads();

    const float4* __restrict__ h2b  = (const float4*)(h2 + (size_t)b * NK * NA);
    const float4* __restrict__ h1s4 = (const float4*)h1s;
    const float4* __restrict__ was4 = (const float4*)was;

    float lg[4][4];
    #pragma unroll
    for (int c = 0; c < 4; ++c) {
        const int k = tid + c * 256;
        const float4* row = h2b + (size_t)k * 32;
        float s0 = 0.f, s1 = 0.f, s2 = 0.f, s3 = 0.f;
        #pragma unroll 8
        for (int a4 = 0; a4 < 32; ++a4) {
            const float4 hv = row[a4];
            const float4 wv = was4[a4];
            const float4 p0 = h1s4[0 * 32 + a4];
            const float4 p1 = h1s4[1 * 32 + a4];
            const float4 p2 = h1s4[2 * 32 + a4];
            const float4 p3 = h1s4[3 * 32 + a4];
            s0 = fmaf(wv.x, fmaxf(p0.x + hv.x, 0.f), s0);
            s0 = fmaf(wv.y, fmaxf(p0.y + hv.y, 0.f), s0);
            s0 = fmaf(wv.z, fmaxf(p0.z + hv.z, 0.f), s0);
            s0 = fmaf(wv.w, fmaxf(p0.w + hv.w, 0.f), s0);
            s1 = fmaf(wv.x, fmaxf(p1.x + hv.x, 0.f), s1);
            s1 = fmaf(wv.y, fmaxf(p1.y + hv.y, 0.f), s1);
            s1 = fmaf(wv.z, fmaxf(p1.z + hv.z, 0.f), s1);
            s1 = fmaf(wv.w, fmaxf(p1.w + hv.w, 0.f), s1);
            s2 = fmaf(wv.x, fmaxf(p2.x + hv.x, 0.f), s2);
            s2 = fmaf(wv.y, fmaxf(p2.y + hv.y, 0.f), s2);
            s2 = fmaf(wv.z, fmaxf(p2.z + hv.z, 0.f), s2);
            s2 = fmaf(wv.w, fmaxf(p2.w + hv.w, 0.f), s2);
            s3 = fmaf(wv.x, fmaxf(p3.x + hv.x, 0.f), s3);
            s3 = fmaf(wv.y, fmaxf(p3.y + hv.y, 0.f), s3);
            s3 = fmaf(wv.z, fmaxf(p3.z + hv.z, 0.f), s3);
            s3 = fmaf(wv.w, fmaxf(p3.w + hv.w, 0.f), s3);
        }
        lg[0][c] = s0; lg[1][c] = s1; lg[2][c] = s2; lg[3][c] = s3;
    }
    // +ba omitted — constant over k, cancels in softmax.

    const int wv_ = tid >> 6, ln = tid & 63;
    float mq[4];
    #pragma unroll
    for (int q = 0; q < 4; ++q) {
        float m = fmaxf(fmaxf(lg[q][0], lg[q][1]), fmaxf(lg[q][2], lg[q][3]));
        for (int off = 32; off > 0; off >>= 1) m = fmaxf(m, __shfl_xor(m, off));
        if (ln == 0) redm[q][wv_] = m;
    }
    __syncthreads();
    #pragma unroll
    for (int q = 0; q < 4; ++q)
        mq[q] = fmaxf(fmaxf(redm[q][0], redm[q][1]), fmaxf(redm[q][2], redm[q][3]));
    #pragma unroll
    for (int q = 0; q < 4; ++q) {
        float s = 0.f;
        #pragma unroll
        for (int c = 0; c < 4; ++c) { lg[q][c] = __expf(lg[q][c] - mq[q]); s += lg[q][c]; }
        for (int off = 32; off > 0; off >>= 1) s += __shfl_xor(s, off);
        if (ln == 0) reds[q][wv_] = s;
    }
    __syncthreads();
    #pragma unroll
    for (int q = 0; q < 4; ++q) {
        const float inv = 1.f / (reds[q][0] + reds[q][1] + reds[q][2] + reds[q][3]);
        __hip_bfloat16* so = score + (size_t)(b * NQ + q0 + q) * NK + tid;
        #pragma unroll
        for (int c = 0; c < 4; ++c) so[c * 256] = __float2bfloat16(lg[q][c] * inv);
    }
}

// ---------------- Kernel 3: PV via MFMA bf16. No LDS, no barriers.
// A = score [M=Q, K], B = value = vt^T ([D,K] stored). BM=32 (2 wave-rows x16),
// BN=64 (2 wave-cols x32). A/B frags use the SAME (lanegroup,elem)->k map, so
// the contraction is correct regardless of the HW's internal k permutation.
// C/D layout (m89-verified): col = lane&15, row = (lane>>4)*4 + reg.
__global__ __launch_bounds__(256) void k_pv(
    const ushort* __restrict__ sc,   // [B][Q][K] bf16 bits
    const ushort* __restrict__ vt,   // [B][D][K] bf16 bits
    float* __restrict__ out)         // [B][Q][D] f32
{
    const int tid = threadIdx.x;
    const int wave = tid >> 6, lane = tid & 63;
    const int wr = wave >> 1, wc = wave & 1;
    const int m0 = blockIdx.x * 32 + wr * 16;
    const int n0 = blockIdx.y * 64 + wc * 32;
    const int b  = blockIdx.z;
    const int l15 = lane & 15, lk = (lane >> 4) * 8;

    const ushort* arow  = sc + (size_t)(b * NQ + m0 + l15) * NK + lk;
    const ushort* b0row = vt + (size_t)(b * ND + n0 + l15) * NK + lk;
    const ushort* b1row = vt + (size_t)(b * ND + n0 + 16 + l15) * NK + lk;

    f32x4 acc0 = {0.f, 0.f, 0.f, 0.f}, acc1 = {0.f, 0.f, 0.f, 0.f};
    #pragma unroll 4
    for (int k = 0; k < NK; k += 32) {
        const short8 a  = *(const short8*)(arow + k);
        const short8 v0 = *(const short8*)(b0row + k);
        const short8 v1 = *(const short8*)(b1row + k);
        acc0 = __builtin_amdgcn_mfma_f32_16x16x32_bf16(a, v0, acc0, 0, 0, 0);
        acc1 = __builtin_amdgcn_mfma_f32_16x16x32_bf16(a, v1, acc1, 0, 0, 0);
    }

    const int orow = (lane >> 4) * 4;
    #pragma unroll
    for (int r = 0; r < 4; ++r) {
        float* po = out + (size_t)(b * NQ + m0 + orow + r) * ND + n0;
        po[l15]      = acc0[r];
        po[16 + l15] = acc1[r];
    }
}

extern "C" void kernel_launch(void* const* d_in, const int* in_sizes, int n_in,
                              void* d_out, int out_size, void* d_ws, size_t ws_size,
                              hipStream_t stream) {
    const float* key   = (const float*)d_in[0];
    const float* query = (const float*)d_in[1];
    const float* value = (const float*)d_in[2];
    const float* Wk    = (const float*)d_in[3];
    const float* bk    = (const float*)d_in[4];
    const float* Wq    = (const float*)d_in[5];
    const float* bq    = (const float*)d_in[6];
    const float* Wa    = (const float*)d_in[7];
    // d_in[8] = ba: cancels in softmax — unused.

    char* ws = (char*)d_ws;
    float* h1 = (float*)(ws + OFFB_H1);
    float* h2 = (float*)(ws + OFFB_H2);
    __hip_bfloat16* sc = (__hip_bfloat16*)(ws + OFFB_SC);
    __hip_bfloat16* vt = (__hip_bfloat16*)(ws + OFFB_VT);

    k_proj_vt<<<672, 256, 0, stream>>>(query, key, value, Wq, bq, Wk, bk, h1, h2, vt);
    k_logits_softmax<<<256, 256, 0, stream>>>(h1, h2, Wa, sc);
    k_pv<<<dim3(8, 8, 4), 256, 0, stream>>>((const ushort*)sc, (const ushort*)vt,
                                            (float*)d_out);
}

// Round 4
// 59.139 us; speedup vs baseline: 1.5890x; 1.2852x over previous
//
#include <hip/hip_runtime.h>
#include <hip/hip_bf16.h>
#include <math.h>

#define NB 4
#define NQ 256
#define NK 1024
#define ND 512
#define NA 128

// ws layout (bytes)
#define OFFB_H1 0u          // NB*NQ*NA f32 = 512 KB
#define OFFB_H2 524288u     // NB*NK*NA f32 = 2 MB
#define OFFB_SC 2621440u    // NB*NQ*NK bf16 = 2 MB
#define OFFB_VT 4718592u    // NB*ND*NK bf16 = 4 MB   (total 8.5 MB)

#define PROJ_BLKS 80        // 5120 rows / 64

typedef __attribute__((ext_vector_type(8))) short short8;
typedef __attribute__((ext_vector_type(8))) unsigned short ushort8_t;
typedef __attribute__((ext_vector_type(4))) float f32x4;

static __device__ __forceinline__ ushort f2bf(float x) {
    __hip_bfloat16 h = __float2bfloat16(x);   // RNE
    return *reinterpret_cast<ushort*>(&h);
}

// LDS address swizzle: row stride 256B; XOR row-bits into bit4-6 and the
// 128B-half bit into bit5 so both fragment reads (stride-256B columns) and
// staging writes avoid bank conflicts. Applied identically on write & read.
static __device__ __forceinline__ unsigned swz(int row, int o) {
    return (unsigned)(row * 256 + (o ^ ((row & 7) << 4) ^ (((o >> 7) & 1) << 5)));
}

// ---------------- Kernel 1: fused {MFMA projections | value transpose+cvt}
// blocks 0..79: 64 rows x 128 cols of h = X@W^T + b via bf16 MFMA (fp32 accum).
//   rows 0..1023 -> h1 (query,Wq,bq); rows 1024..5119 -> h2 (key,Wk,bk).
// blocks 80..591: vt[b][d][k] = bf16(value[b][k][d]).
__global__ __launch_bounds__(256) void k_proj_vt(
    const float* __restrict__ query, const float* __restrict__ key,
    const float* __restrict__ value,
    const float* __restrict__ Wq, const float* __restrict__ bq,
    const float* __restrict__ Wk, const float* __restrict__ bk,
    float* __restrict__ h1, float* __restrict__ h2,
    __hip_bfloat16* __restrict__ vt)
{
    __shared__ __align__(16) ushort smem[24576];  // 48KB: Xs 16KB @0, Ws 32KB @16384B
    char* sbytes = (char*)smem;
    const int tid = threadIdx.x;
    const int bid = blockIdx.x;

    if (bid < PROJ_BLKS) {
        const int r0 = bid * 64;
        const bool isQ = r0 < NB * NQ;
        const float* X    = isQ ? query + (size_t)r0 * ND : key + (size_t)(r0 - NB * NQ) * ND;
        const float* W    = isQ ? Wq : Wk;
        const float* bias = isQ ? bq : bk;
        float* hout       = isQ ? h1 + (size_t)r0 * NA : h2 + (size_t)(r0 - NB * NQ) * NA;

        const int wave = tid >> 6, lane = tid & 63;
        const int l15 = lane & 15, lkb = (lane >> 4) * 16;   // k byte-offset in frag

        f32x4 acc[8] = {};

        for (int kc = 0; kc < ND; kc += 128) {
            __syncthreads();
            {   // stage X chunk: 64 rows x 128 k, f32 -> bf16, swizzled
                const int row = tid >> 2, kg = (tid & 3) * 32;
                const float* src = X + (size_t)row * ND + kc + kg;
                #pragma unroll
                for (int j = 0; j < 4; ++j) {
                    const float4 v0 = *(const float4*)(src + j * 8);
                    const float4 v1 = *(const float4*)(src + j * 8 + 4);
                    ushort8_t o;
                    o[0] = f2bf(v0.x); o[1] = f2bf(v0.y); o[2] = f2bf(v0.z); o[3] = f2bf(v0.w);
                    o[4] = f2bf(v1.x); o[5] = f2bf(v1.y); o[6] = f2bf(v1.z); o[7] = f2bf(v1.w);
                    *(ushort8_t*)(sbytes + swz(row, kg * 2 + j * 16)) = o;
                }
            }
            {   // stage W chunk: 128 cols x 128 k, f32 -> bf16, swizzled
                const int row = tid >> 1, kg = (tid & 1) * 64;
                const float* src = W + (size_t)row * ND + kc + kg;
                #pragma unroll
                for (int j = 0; j < 8; ++j) {
                    const float4 v0 = *(const float4*)(src + j * 8);
                    const float4 v1 = *(const float4*)(src + j * 8 + 4);
                    ushort8_t o;
                    o[0] = f2bf(v0.x); o[1] = f2bf(v0.y); o[2] = f2bf(v0.z); o[3] = f2bf(v0.w);
                    o[4] = f2bf(v1.x); o[5] = f2bf(v1.y); o[6] = f2bf(v1.z); o[7] = f2bf(v1.w);
                    *(ushort8_t*)(sbytes + 16384 + swz(row, kg * 2 + j * 16)) = o;
                }
            }
            __syncthreads();
            // MFMA: wave w -> rows w*16..+15, all 8 col-tiles. A/B frags read
            // the same [row][k] LDS layout with the same lane->k map, so the
            // contraction is k-permutation-safe (validated by round-3 k_pv).
            #pragma unroll
            for (int kk = 0; kk < 4; ++kk) {
                const int arow = wave * 16 + l15;
                const short8 a = *(const short8*)(sbytes + swz(arow, kk * 64 + lkb));
                #pragma unroll
                for (int ct = 0; ct < 8; ++ct) {
                    const int bcol = ct * 16 + l15;
                    const short8 b = *(const short8*)(sbytes + 16384 + swz(bcol, kk * 64 + lkb));
                    acc[ct] = __builtin_amdgcn_mfma_f32_16x16x32_bf16(a, b, acc[ct], 0, 0, 0);
                }
            }
        }

        // epilogue: C/D layout col=lane&15, row=(lane>>4)*4+r (m89-verified)
        const int orow0 = wave * 16 + (lane >> 4) * 4;
        #pragma unroll
        for (int ct = 0; ct < 8; ++ct) {
            const int col = ct * 16 + l15;
            const float bb = bias[col];
            #pragma unroll
            for (int r = 0; r < 4; ++r)
                hout[(size_t)(orow0 + r) * NA + col] = acc[ct][r] + bb;
        }
    } else {
        // value transpose + bf16 convert: 64k x 64d tile
        ushort (*tile)[65] = (ushort (*)[65])smem;
        const int id = bid - PROJ_BLKS;    // 0..511
        const int kt = id & 15;            // 16 k-tiles
        const int dt = (id >> 4) & 7;      // 8 d-tiles
        const int b  = id >> 7;            // 4 batches
        const int k0 = kt * 64, d0 = dt * 64;
        const int tr = tid >> 4, tc4 = (tid & 15) * 4;

        #pragma unroll
        for (int p = 0; p < 4; ++p) {
            const int r = p * 16 + tr;     // k-row within tile
            const float4 v = *(const float4*)(value + ((size_t)(b * NK + k0 + r)) * ND + d0 + tc4);
            tile[r][tc4 + 0] = f2bf(v.x); tile[r][tc4 + 1] = f2bf(v.y);
            tile[r][tc4 + 2] = f2bf(v.z); tile[r][tc4 + 3] = f2bf(v.w);
        }
        __syncthreads();
        ushort* vo = (ushort*)vt;
        #pragma unroll
        for (int p = 0; p < 4; ++p) {
            const int d = p * 16 + tr;     // d-row within tile
            ushort4 o;
            o.x = tile[tc4 + 0][d]; o.y = tile[tc4 + 1][d];
            o.z = tile[tc4 + 2][d]; o.w = tile[tc4 + 3][d];
            *(ushort4*)(vo + ((size_t)(b * ND + d0 + d)) * NK + k0 + tc4) = o;
        }
    }
}

// ---------------- Kernel 2: logits + softmax -> score (bf16)
// block = (b, 4 q-rows), 512 threads (8 waves = 2 waves/SIMD for latency hiding).
// thread handles k = tid + 512c (c=0..1) for all 4 q.
__global__ __launch_bounds__(512) void k_logits_softmax(
    const float* __restrict__ h1, const float* __restrict__ h2,
    const float* __restrict__ Wa, __hip_bfloat16* __restrict__ score)
{
    __shared__ float h1s[4 * 128];
    __shared__ float was[128];
    __shared__ float redm[4][8];
    __shared__ float reds[4][8];
    const int tid = threadIdx.x;
    const int b = blockIdx.x >> 6;
    const int q0 = (blockIdx.x & 63) << 2;

    {
        const int q = tid >> 7, a = tid & 127;   // tid 0..511 covers 4x128
        h1s[tid] = h1[(size_t)(b * NQ + q0 + q) * NA + a];
    }
    if (tid < 128) was[tid] = Wa[tid];
    __syncthreads();

    const float4* __restrict__ h2b  = (const float4*)(h2 + (size_t)b * NK * NA);
    const float4* __restrict__ h1s4 = (const float4*)h1s;
    const float4* __restrict__ was4 = (const float4*)was;

    float lg[4][2];
    #pragma unroll
    for (int c = 0; c < 2; ++c) {
        const int k = tid + c * 512;
        const float4* row = h2b + (size_t)k * 32;
        float s0 = 0.f, s1 = 0.f, s2 = 0.f, s3 = 0.f;
        #pragma unroll 8
        for (int a4 = 0; a4 < 32; ++a4) {
            const float4 hv = row[a4];
            const float4 wv = was4[a4];
            const float4 p0 = h1s4[0 * 32 + a4];
            const float4 p1 = h1s4[1 * 32 + a4];
            const float4 p2 = h1s4[2 * 32 + a4];
            const float4 p3 = h1s4[3 * 32 + a4];
            s0 = fmaf(wv.x, fmaxf(p0.x + hv.x, 0.f), s0);
            s0 = fmaf(wv.y, fmaxf(p0.y + hv.y, 0.f), s0);
            s0 = fmaf(wv.z, fmaxf(p0.z + hv.z, 0.f), s0);
            s0 = fmaf(wv.w, fmaxf(p0.w + hv.w, 0.f), s0);
            s1 = fmaf(wv.x, fmaxf(p1.x + hv.x, 0.f), s1);
            s1 = fmaf(wv.y, fmaxf(p1.y + hv.y, 0.f), s1);
            s1 = fmaf(wv.z, fmaxf(p1.z + hv.z, 0.f), s1);
            s1 = fmaf(wv.w, fmaxf(p1.w + hv.w, 0.f), s1);
            s2 = fmaf(wv.x, fmaxf(p2.x + hv.x, 0.f), s2);
            s2 = fmaf(wv.y, fmaxf(p2.y + hv.y, 0.f), s2);
            s2 = fmaf(wv.z, fmaxf(p2.z + hv.z, 0.f), s2);
            s2 = fmaf(wv.w, fmaxf(p2.w + hv.w, 0.f), s2);
            s3 = fmaf(wv.x, fmaxf(p3.x + hv.x, 0.f), s3);
            s3 = fmaf(wv.y, fmaxf(p3.y + hv.y, 0.f), s3);
            s3 = fmaf(wv.z, fmaxf(p3.z + hv.z, 0.f), s3);
            s3 = fmaf(wv.w, fmaxf(p3.w + hv.w, 0.f), s3);
        }
        lg[0][c] = s0; lg[1][c] = s1; lg[2][c] = s2; lg[3][c] = s3;
    }
    // +ba omitted — constant over k, cancels in softmax.

    const int wv_ = tid >> 6, ln = tid & 63;
    float mq[4];
    #pragma unroll
    for (int q = 0; q < 4; ++q) {
        float m = fmaxf(lg[q][0], lg[q][1]);
        for (int off = 32; off > 0; off >>= 1) m = fmaxf(m, __shfl_xor(m, off));
        if (ln == 0) redm[q][wv_] = m;
    }
    __syncthreads();
    #pragma unroll
    for (int q = 0; q < 4; ++q) {
        float m = redm[q][0];
        #pragma unroll
        for (int w = 1; w < 8; ++w) m = fmaxf(m, redm[q][w]);
        mq[q] = m;
    }
    #pragma unroll
    for (int q = 0; q < 4; ++q) {
        float s = 0.f;
        #pragma unroll
        for (int c = 0; c < 2; ++c) { lg[q][c] = __expf(lg[q][c] - mq[q]); s += lg[q][c]; }
        for (int off = 32; off > 0; off >>= 1) s += __shfl_xor(s, off);
        if (ln == 0) reds[q][wv_] = s;
    }
    __syncthreads();
    #pragma unroll
    for (int q = 0; q < 4; ++q) {
        float s = reds[q][0];
        #pragma unroll
        for (int w = 1; w < 8; ++w) s += reds[q][w];
        const float inv = 1.f / s;
        __hip_bfloat16* so = score + (size_t)(b * NQ + q0 + q) * NK + tid;
        #pragma unroll
        for (int c = 0; c < 2; ++c) so[c * 512] = __float2bfloat16(lg[q][c] * inv);
    }
}

// ---------------- Kernel 3: PV via MFMA bf16. No LDS, no barriers.
// A = score [M=Q, K], B = vt ([D,K] stored). Same-k-map trick; C/D per m89.
__global__ __launch_bounds__(256) void k_pv(
    const ushort* __restrict__ sc,   // [B][Q][K] bf16 bits
    const ushort* __restrict__ vt,   // [B][D][K] bf16 bits
    float* __restrict__ out)         // [B][Q][D] f32
{
    const int tid = threadIdx.x;
    const int wave = tid >> 6, lane = tid & 63;
    const int wr = wave >> 1, wc = wave & 1;
    const int m0 = blockIdx.x * 32 + wr * 16;
    const int n0 = blockIdx.y * 64 + wc * 32;
    const int b  = blockIdx.z;
    const int l15 = lane & 15, lk = (lane >> 4) * 8;

    const ushort* arow  = sc + (size_t)(b * NQ + m0 + l15) * NK + lk;
    const ushort* b0row = vt + (size_t)(b * ND + n0 + l15) * NK + lk;
    const ushort* b1row = vt + (size_t)(b * ND + n0 + 16 + l15) * NK + lk;

    f32x4 acc0 = {0.f, 0.f, 0.f, 0.f}, acc1 = {0.f, 0.f, 0.f, 0.f};
    #pragma unroll 4
    for (int k = 0; k < NK; k += 32) {
        const short8 a  = *(const short8*)(arow + k);
        const short8 v0 = *(const short8*)(b0row + k);
        const short8 v1 = *(const short8*)(b1row + k);
        acc0 = __builtin_amdgcn_mfma_f32_16x16x32_bf16(a, v0, acc0, 0, 0, 0);
        acc1 = __builtin_amdgcn_mfma_f32_16x16x32_bf16(a, v1, acc1, 0, 0, 0);
    }

    const int orow = (lane >> 4) * 4;
    #pragma unroll
    for (int r = 0; r < 4; ++r) {
        float* po = out + (size_t)(b * NQ + m0 + orow + r) * ND + n0;
        po[l15]      = acc0[r];
        po[16 + l15] = acc1[r];
    }
}

extern "C" void kernel_launch(void* const* d_in, const int* in_sizes, int n_in,
                              void* d_out, int out_size, void* d_ws, size_t ws_size,
                              hipStream_t stream) {
    const float* key   = (const float*)d_in[0];
    const float* query = (const float*)d_in[1];
    const float* value = (const float*)d_in[2];
    const float* Wk    = (const float*)d_in[3];
    const float* bk    = (const float*)d_in[4];
    const float* Wq    = (const float*)d_in[5];
    const float* bq    = (const float*)d_in[6];
    const float* Wa    = (const float*)d_in[7];
    // d_in[8] = ba: cancels in softmax — unused.

    char* ws = (char*)d_ws;
    float* h1 = (float*)(ws + OFFB_H1);
    float* h2 = (float*)(ws + OFFB_H2);
    __hip_bfloat16* sc = (__hip_bfloat16*)(ws + OFFB_SC);
    __hip_bfloat16* vt = (__hip_bfloat16*)(ws + OFFB_VT);

    k_proj_vt<<<PROJ_BLKS + 512, 256, 0, stream>>>(query, key, value, Wq, bq, Wk, bk,
                                                   h1, h2, vt);
    k_logits_softmax<<<256, 512, 0, stream>>>(h1, h2, Wa, sc);
    k_pv<<<dim3(8, 8, 4), 256, 0, stream>>>((const ushort*)sc, (const ushort*)vt,
                                            (float*)d_out);
}

// Round 5
// 59.053 us; speedup vs baseline: 1.5913x; 1.0015x over previous
//
#include <hip/hip_runtime.h>
#include <hip/hip_bf16.h>
#include <math.h>

#define NB 4
#define NQ 256
#define NK 1024
#define ND 512
#define NA 128

// ws layout (bytes)
#define OFFB_H1 0u          // NB*NQ*NA f32 = 512 KB
#define OFFB_H2 524288u     // NB*NK*NA f32 = 2 MB
#define OFFB_SC 2621440u    // NB*NQ*NK bf16 = 2 MB
#define OFFB_VT 4718592u    // NB*ND*NK bf16 = 4 MB   (total 8.5 MB)

#define PROJ_BLKS 80        // 5120 rows / 64

typedef __attribute__((ext_vector_type(8))) short short8;
typedef __attribute__((ext_vector_type(8))) unsigned short ushort8_t;
typedef __attribute__((ext_vector_type(4))) float f32x4;

static __device__ __forceinline__ ushort f2bf(float x) {
    __hip_bfloat16 h = __float2bfloat16(x);   // RNE
    return *reinterpret_cast<ushort*>(&h);
}

// LDS address swizzle: row stride 256B; XOR row-bits into bit4-6 and the
// 128B-half bit into bit5 so both fragment reads (stride-256B columns) and
// staging writes avoid bank conflicts. Applied identically on write & read.
static __device__ __forceinline__ unsigned swz(int row, int o) {
    return (unsigned)(row * 256 + (o ^ ((row & 7) << 4) ^ (((o >> 7) & 1) << 5)));
}

// ---------------- Kernel 1: fused {MFMA projections | value transpose+cvt}
// blocks 0..79: 64 rows x 128 cols of h = X@W^T + b via bf16 MFMA (fp32 accum).
//   rows 0..1023 -> h1 (query,Wq,bq); rows 1024..5119 -> h2 (key,Wk,bk).
// blocks 80..591: vt[b][d][k] = bf16(value[b][k][d]).
__global__ __launch_bounds__(256) void k_proj_vt(
    const float* __restrict__ query, const float* __restrict__ key,
    const float* __restrict__ value,
    const float* __restrict__ Wq, const float* __restrict__ bq,
    const float* __restrict__ Wk, const float* __restrict__ bk,
    float* __restrict__ h1, float* __restrict__ h2,
    __hip_bfloat16* __restrict__ vt)
{
    __shared__ __align__(16) ushort smem[24576];  // 48KB: Xs 16KB @0, Ws 32KB @16384B
    char* sbytes = (char*)smem;
    const int tid = threadIdx.x;
    const int bid = blockIdx.x;

    if (bid < PROJ_BLKS) {
        const int r0 = bid * 64;
        const bool isQ = r0 < NB * NQ;
        const float* X    = isQ ? query + (size_t)r0 * ND : key + (size_t)(r0 - NB * NQ) * ND;
        const float* W    = isQ ? Wq : Wk;
        const float* bias = isQ ? bq : bk;
        float* hout       = isQ ? h1 + (size_t)r0 * NA : h2 + (size_t)(r0 - NB * NQ) * NA;

        const int wave = tid >> 6, lane = tid & 63;
        const int l15 = lane & 15, lkb = (lane >> 4) * 16;   // k byte-offset in frag

        f32x4 acc[8] = {};

        for (int kc = 0; kc < ND; kc += 128) {
            __syncthreads();
            {   // stage X chunk: 64 rows x 128 k, f32 -> bf16, swizzled
                const int row = tid >> 2, kg = (tid & 3) * 32;
                const float* src = X + (size_t)row * ND + kc + kg;
                #pragma unroll
                for (int j = 0; j < 4; ++j) {
                    const float4 v0 = *(const float4*)(src + j * 8);
                    const float4 v1 = *(const float4*)(src + j * 8 + 4);
                    ushort8_t o;
                    o[0] = f2bf(v0.x); o[1] = f2bf(v0.y); o[2] = f2bf(v0.z); o[3] = f2bf(v0.w);
                    o[4] = f2bf(v1.x); o[5] = f2bf(v1.y); o[6] = f2bf(v1.z); o[7] = f2bf(v1.w);
                    *(ushort8_t*)(sbytes + swz(row, kg * 2 + j * 16)) = o;
                }
            }
            {   // stage W chunk: 128 cols x 128 k, f32 -> bf16, swizzled
                const int row = tid >> 1, kg = (tid & 1) * 64;
                const float* src = W + (size_t)row * ND + kc + kg;
                #pragma unroll
                for (int j = 0; j < 8; ++j) {
                    const float4 v0 = *(const float4*)(src + j * 8);
                    const float4 v1 = *(const float4*)(src + j * 8 + 4);
                    ushort8_t o;
                    o[0] = f2bf(v0.x); o[1] = f2bf(v0.y); o[2] = f2bf(v0.z); o[3] = f2bf(v0.w);
                    o[4] = f2bf(v1.x); o[5] = f2bf(v1.y); o[6] = f2bf(v1.z); o[7] = f2bf(v1.w);
                    *(ushort8_t*)(sbytes + 16384 + swz(row, kg * 2 + j * 16)) = o;
                }
            }
            __syncthreads();
            // MFMA: wave w -> rows w*16..+15, all 8 col-tiles. A/B frags read
            // the same [row][k] LDS layout with the same lane->k map, so the
            // contraction is k-permutation-safe (validated by round-3 k_pv).
            #pragma unroll
            for (int kk = 0; kk < 4; ++kk) {
                const int arow = wave * 16 + l15;
                const short8 a = *(const short8*)(sbytes + swz(arow, kk * 64 + lkb));
                #pragma unroll
                for (int ct = 0; ct < 8; ++ct) {
                    const int bcol = ct * 16 + l15;
                    const short8 b = *(const short8*)(sbytes + 16384 + swz(bcol, kk * 64 + lkb));
                    acc[ct] = __builtin_amdgcn_mfma_f32_16x16x32_bf16(a, b, acc[ct], 0, 0, 0);
                }
            }
        }

        // epilogue: C/D layout col=lane&15, row=(lane>>4)*4+r (m89-verified)
        const int orow0 = wave * 16 + (lane >> 4) * 4;
        #pragma unroll
        for (int ct = 0; ct < 8; ++ct) {
            const int col = ct * 16 + l15;
            const float bb = bias[col];
            #pragma unroll
            for (int r = 0; r < 4; ++r)
                hout[(size_t)(orow0 + r) * NA + col] = acc[ct][r] + bb;
        }
    } else {
        // value transpose + bf16 convert: 64k x 64d tile
        ushort (*tile)[65] = (ushort (*)[65])smem;
        const int id = bid - PROJ_BLKS;    // 0..511
        const int kt = id & 15;            // 16 k-tiles
        const int dt = (id >> 4) & 7;      // 8 d-tiles
        const int b  = id >> 7;            // 4 batches
        const int k0 = kt * 64, d0 = dt * 64;
        const int tr = tid >> 4, tc4 = (tid & 15) * 4;

        #pragma unroll
        for (int p = 0; p < 4; ++p) {
            const int r = p * 16 + tr;     // k-row within tile
            const float4 v = *(const float4*)(value + ((size_t)(b * NK + k0 + r)) * ND + d0 + tc4);
            tile[r][tc4 + 0] = f2bf(v.x); tile[r][tc4 + 1] = f2bf(v.y);
            tile[r][tc4 + 2] = f2bf(v.z); tile[r][tc4 + 3] = f2bf(v.w);
        }
        __syncthreads();
        ushort* vo = (ushort*)vt;
        #pragma unroll
        for (int p = 0; p < 4; ++p) {
            const int d = p * 16 + tr;     // d-row within tile
            ushort4 o;
            o.x = tile[tc4 + 0][d]; o.y = tile[tc4 + 1][d];
            o.z = tile[tc4 + 2][d]; o.w = tile[tc4 + 3][d];
            *(ushort4*)(vo + ((size_t)(b * ND + d0 + d)) * NK + k0 + tc4) = o;
        }
    }
}

// ---------------- Kernel 2: logits + softmax -> score (bf16)
// block = (b, 4 q-rows), 512 threads. Thread handles k = tid + 512c (c=0..1).
// h1 rows and Wa are read with WAVE-UNIFORM addresses straight from global:
// the compiler lowers these to s_load (scalar pipe, K$-resident ~2.5KB) or a
// broadcast vector load — either way the hot loop issues ZERO LDS reads
// (the r4 version burned ~12 µs of per-CU ds_read_b128 issue slots on
// broadcast h1s/Wa reads). Only the per-lane h2 float4 load remains.
__global__ __launch_bounds__(512) void k_logits_softmax(
    const float* __restrict__ h1, const float* __restrict__ h2,
    const float* __restrict__ Wa, __hip_bfloat16* __restrict__ score)
{
    __shared__ float redm[4][8];
    __shared__ float reds[4][8];
    const int tid = threadIdx.x;
    const int b = blockIdx.x >> 6;
    const int q0 = (blockIdx.x & 63) << 2;

    const float4* __restrict__ h2b = (const float4*)(h2 + (size_t)b * NK * NA);
    const float4* __restrict__ h1g = (const float4*)(h1 + (size_t)(b * NQ + q0) * NA);
    const float4* __restrict__ wag = (const float4*)Wa;

    float lg[4][2];
    #pragma unroll
    for (int c = 0; c < 2; ++c) {
        const int k = tid + c * 512;
        const float4* row = h2b + (size_t)k * 32;
        float s0 = 0.f, s1 = 0.f, s2 = 0.f, s3 = 0.f;
        #pragma unroll 8
        for (int a4 = 0; a4 < 32; ++a4) {
            const float4 hv = row[a4];         // per-lane (L2)
            const float4 wv = wag[a4];         // wave-uniform -> scalar
            const float4 p0 = h1g[0 * 32 + a4];
            const float4 p1 = h1g[1 * 32 + a4];
            const float4 p2 = h1g[2 * 32 + a4];
            const float4 p3 = h1g[3 * 32 + a4];
            s0 = fmaf(wv.x, fmaxf(p0.x + hv.x, 0.f), s0);
            s0 = fmaf(wv.y, fmaxf(p0.y + hv.y, 0.f), s0);
            s0 = fmaf(wv.z, fmaxf(p0.z + hv.z, 0.f), s0);
            s0 = fmaf(wv.w, fmaxf(p0.w + hv.w, 0.f), s0);
            s1 = fmaf(wv.x, fmaxf(p1.x + hv.x, 0.f), s1);
            s1 = fmaf(wv.y, fmaxf(p1.y + hv.y, 0.f), s1);
            s1 = fmaf(wv.z, fmaxf(p1.z + hv.z, 0.f), s1);
            s1 = fmaf(wv.w, fmaxf(p1.w + hv.w, 0.f), s1);
            s2 = fmaf(wv.x, fmaxf(p2.x + hv.x, 0.f), s2);
            s2 = fmaf(wv.y, fmaxf(p2.y + hv.y, 0.f), s2);
            s2 = fmaf(wv.z, fmaxf(p2.z + hv.z, 0.f), s2);
            s2 = fmaf(wv.w, fmaxf(p2.w + hv.w, 0.f), s2);
            s3 = fmaf(wv.x, fmaxf(p3.x + hv.x, 0.f), s3);
            s3 = fmaf(wv.y, fmaxf(p3.y + hv.y, 0.f), s3);
            s3 = fmaf(wv.z, fmaxf(p3.z + hv.z, 0.f), s3);
            s3 = fmaf(wv.w, fmaxf(p3.w + hv.w, 0.f), s3);
        }
        lg[0][c] = s0; lg[1][c] = s1; lg[2][c] = s2; lg[3][c] = s3;
    }
    // +ba omitted — constant over k, cancels in softmax.

    const int wv_ = tid >> 6, ln = tid & 63;
    float mq[4];
    #pragma unroll
    for (int q = 0; q < 4; ++q) {
        float m = fmaxf(lg[q][0], lg[q][1]);
        for (int off = 32; off > 0; off >>= 1) m = fmaxf(m, __shfl_xor(m, off));
        if (ln == 0) redm[q][wv_] = m;
    }
    __syncthreads();
    #pragma unroll
    for (int q = 0; q < 4; ++q) {
        float m = redm[q][0];
        #pragma unroll
        for (int w = 1; w < 8; ++w) m = fmaxf(m, redm[q][w]);
        mq[q] = m;
    }
    #pragma unroll
    for (int q = 0; q < 4; ++q) {
        float s = 0.f;
        #pragma unroll
        for (int c = 0; c < 2; ++c) { lg[q][c] = __expf(lg[q][c] - mq[q]); s += lg[q][c]; }
        for (int off = 32; off > 0; off >>= 1) s += __shfl_xor(s, off);
        if (ln == 0) reds[q][wv_] = s;
    }
    __syncthreads();
    #pragma unroll
    for (int q = 0; q < 4; ++q) {
        float s = reds[q][0];
        #pragma unroll
        for (int w = 1; w < 8; ++w) s += reds[q][w];
        const float inv = 1.f / s;
        __hip_bfloat16* so = score + (size_t)(b * NQ + q0 + q) * NK + tid;
        #pragma unroll
        for (int c = 0; c < 2; ++c) so[c * 512] = __float2bfloat16(lg[q][c] * inv);
    }
}

// ---------------- Kernel 3: PV via MFMA bf16. No LDS, no barriers.
// A = score [M=Q, K], B = vt ([D,K] stored). Same-k-map trick; C/D per m89.
__global__ __launch_bounds__(256) void k_pv(
    const ushort* __restrict__ sc,   // [B][Q][K] bf16 bits
    const ushort* __restrict__ vt,   // [B][D][K] bf16 bits
    float* __restrict__ out)         // [B][Q][D] f32
{
    const int tid = threadIdx.x;
    const int wave = tid >> 6, lane = tid & 63;
    const int wr = wave >> 1, wc = wave & 1;
    const int m0 = blockIdx.x * 32 + wr * 16;
    const int n0 = blockIdx.y * 64 + wc * 32;
    const int b  = blockIdx.z;
    const int l15 = lane & 15, lk = (lane >> 4) * 8;

    const ushort* arow  = sc + (size_t)(b * NQ + m0 + l15) * NK + lk;
    const ushort* b0row = vt + (size_t)(b * ND + n0 + l15) * NK + lk;
    const ushort* b1row = vt + (size_t)(b * ND + n0 + 16 + l15) * NK + lk;

    f32x4 acc0 = {0.f, 0.f, 0.f, 0.f}, acc1 = {0.f, 0.f, 0.f, 0.f};
    #pragma unroll 4
    for (int k = 0; k < NK; k += 32) {
        const short8 a  = *(const short8*)(arow + k);
        const short8 v0 = *(const short8*)(b0row + k);
        const short8 v1 = *(const short8*)(b1row + k);
        acc0 = __builtin_amdgcn_mfma_f32_16x16x32_bf16(a, v0, acc0, 0, 0, 0);
        acc1 = __builtin_amdgcn_mfma_f32_16x16x32_bf16(a, v1, acc1, 0, 0, 0);
    }

    const int orow = (lane >> 4) * 4;
    #pragma unroll
    for (int r = 0; r < 4; ++r) {
        float* po = out + (size_t)(b * NQ + m0 + orow + r) * ND + n0;
        po[l15]      = acc0[r];
        po[16 + l15] = acc1[r];
    }
}

extern "C" void kernel_launch(void* const* d_in, const int* in_sizes, int n_in,
                              void* d_out, int out_size, void* d_ws, size_t ws_size,
                              hipStream_t stream) {
    const float* key   = (const float*)d_in[0];
    const float* query = (const float*)d_in[1];
    const float* value = (const float*)d_in[2];
    const float* Wk    = (const float*)d_in[3];
    const float* bk    = (const float*)d_in[4];
    const float* Wq    = (const float*)d_in[5];
    const float* bq    = (const float*)d_in[6];
    const float* Wa    = (const float*)d_in[7];
    // d_in[8] = ba: cancels in softmax — unused.

    char* ws = (char*)d_ws;
    float* h1 = (float*)(ws + OFFB_H1);
    float* h2 = (float*)(ws + OFFB_H2);
    __hip_bfloat16* sc = (__hip_bfloat16*)(ws + OFFB_SC);
    __hip_bfloat16* vt = (__hip_bfloat16*)(ws + OFFB_VT);

    k_proj_vt<<<PROJ_BLKS + 512, 256, 0, stream>>>(query, key, value, Wq, bq, Wk, bk,
                                                   h1, h2, vt);
    k_logits_softmax<<<256, 512, 0, stream>>>(h1, h2, Wa, sc);
    k_pv<<<dim3(8, 8, 4), 256, 0, stream>>>((const ushort*)sc, (const ushort*)vt,
                                            (float*)d_out);
}